// Round 11
// baseline (185.843 us; speedup 1.0000x reference)
//
#include <hip/hip_runtime.h>
#include <hip/hip_fp16.h>

// ---------------------------------------------------------------------------
// GATv2 (2 layers), bucket + in-block dst-sort formulation.
// Bucket = dst >> 6 (64 nodes/bucket, 782 buckets). Scatter = block-level
// counting sort into bucket-grouped global buf (coalesced full lines).
// gather1 (512 thr / 8 waves -> 4 blocks/CU, no straggler round): in-block
// counting sort by dst -> per-node contiguous segments -> wave accumulates
// its 8 nodes' segments in REGISTERS, 4-deep gather pipeline. Zero fp atomics
// (R8/R9 lesson: per-edge LDS fp-atomic wave-ops serialize block-wide).
// xl is stored as fp16 (gemm writes half): halves the dominant per-edge
// gather traffic (256B->128B per edge); fp16 eps 5e-4 << 6e-3 threshold.
// gather2: edge-parallel, scalar LDS fp atomics (few wave-ops, negligible).
// 8-lane head reduction via DPP; exp2 with log2e prefolded. Softmax without
// max-subtraction (scores O(10), exp fp32-safe; shift-invariant). Self-loops
// handled analytically, never stored.
// ---------------------------------------------------------------------------

#define NEG_SLOPE 0.2f
#define LOG2E 1.4426950408889634f
#define CB_SHIFT 6
#define CB_MASK 63
#define CAP_C 3072     // mean 2048/bucket, sigma~45 -> 22-sigma headroom
#define CHUNK 8192     // edges per scatter block (8 per thread)
#define CNT_STRIDE 32  // one counter per 128B

#if __has_builtin(__builtin_amdgcn_exp2f)
#define EXP2(x) __builtin_amdgcn_exp2f(x)
#else
#define EXP2(x) __expf((x)*0.6931471805599453f)
#endif

__device__ __forceinline__ void lds_fadd(float* p, float v) {
  unsafeAtomicAdd(p, v);
}

// 8-lane-group sum via DPP: quad_perm swap1, swap2, row_half_mirror.
__device__ __forceinline__ float dpp_add_xor1(float x) {
  int v = __builtin_amdgcn_update_dpp(0, __float_as_int(x), 0xB1, 0xF, 0xF, true);
  return x + __int_as_float(v);
}
__device__ __forceinline__ float dpp_add_xor2(float x) {
  int v = __builtin_amdgcn_update_dpp(0, __float_as_int(x), 0x4E, 0xF, 0xF, true);
  return x + __int_as_float(v);
}
__device__ __forceinline__ float dpp_add_half_mirror(float x) {
  int v = __builtin_amdgcn_update_dpp(0, __float_as_int(x), 0x141, 0xF, 0xF, true);
  return x + __int_as_float(v);
}
__device__ __forceinline__ float head8_sum(float x) {
  return dpp_add_half_mirror(dpp_add_xor2(dpp_add_xor1(x)));
}

// Dual GEMM, split grid: blocks [0,half) -> xl (fp16), [half,2*half) -> xr
// (fp32). Lane j holds W[:,j] in 128 VGPRs; x broadcast via readlane.
__global__ __launch_bounds__(256) void gemm_reg_dual(
    const float* __restrict__ x, const float* __restrict__ Wl,
    const float* __restrict__ Wr, __half* __restrict__ xlh,
    float* __restrict__ xr, int N, int half_blocks) {
  bool second = blockIdx.x >= half_blocks;
  int bid = second ? blockIdx.x - half_blocks : blockIdx.x;
  const float* __restrict__ W = second ? Wr : Wl;
  int nwaves = half_blocks * 4;
  int wid = bid * 4 + (threadIdx.x >> 6);
  int j = threadIdx.x & 63;
  float Wcol[128];
#pragma unroll
  for (int k = 0; k < 128; ++k) Wcol[k] = W[k * 64 + j];  // coalesced, L2-hot
  for (int n = wid; n < N; n += nwaves) {
    const float2 xv2 = *(const float2*)&x[(size_t)n * 128 + 2 * j];
    float xa = xv2.x, xb = xv2.y;  // lane l holds x[n][2l], x[n][2l+1]
    float acc0 = 0.f, acc1 = 0.f;
#pragma unroll
    for (int k = 0; k < 128; k += 2) {
      unsigned b0 = __builtin_amdgcn_readlane(__float_as_uint(xa), k >> 1);
      unsigned b1 = __builtin_amdgcn_readlane(__float_as_uint(xb), k >> 1);
      acc0 = fmaf(__uint_as_float(b0), Wcol[k], acc0);
      acc1 = fmaf(__uint_as_float(b1), Wcol[k + 1], acc1);
    }
    if (second) xr[(size_t)n * 64 + j] = acc0 + acc1;
    else        xlh[(size_t)n * 64 + j] = __float2half(acc0 + acc1);
  }
}

// Block-level counting-sort scatter: CHUNK edges -> bucket-grouped global buf.
__global__ __launch_bounds__(1024) void bucket_scatter(
    const int* __restrict__ ei, int E0, int* __restrict__ bcnt,
    int* __restrict__ buf) {
  __shared__ int hist[1024];          // per-bucket counts (782 used)
  __shared__ int sc[1024];            // scan / later: exclusive seg start
  __shared__ int gofs[1024];          // bucket_base + global_rank - seg_start
  __shared__ unsigned stage[CHUNK];   // (bucket<<22) | entry, bucket-grouped
  int tid = threadIdx.x;
  int base = blockIdx.x * CHUNK;
  hist[tid] = 0;
  __syncthreads();
  int bb[8], pp[8], ent[8];
#pragma unroll
  for (int r = 0; r < 8; ++r) {
    int e = base + r * 1024 + tid;
    if (e < E0) {
      int s = ei[e], d = ei[E0 + e];
      int b = d >> CB_SHIFT;
      bb[r] = b;
      ent[r] = (s << CB_SHIFT) | (d & CB_MASK);
      pp[r] = atomicAdd(&hist[b], 1);  // int LDS atomic: native, fast
    } else {
      bb[r] = -1;
    }
  }
  __syncthreads();
  int v = hist[tid];
  sc[tid] = v;
  __syncthreads();
  for (int off = 1; off < 1024; off <<= 1) {  // Hillis-Steele inclusive scan
    int u = (tid >= off) ? sc[tid - off] : 0;
    __syncthreads();
    sc[tid] += u;
    __syncthreads();
  }
  int total = sc[1023];
  int excl = sc[tid] - v;
  int gb = 0;
  if (v > 0) gb = atomicAdd(&bcnt[tid * CNT_STRIDE], v);  // reserve range
  __syncthreads();
  sc[tid] = excl;                        // seg start of bucket `tid` in stage[]
  gofs[tid] = tid * CAP_C + gb - excl;   // write addr = gofs[bucket] + stage_idx
  __syncthreads();
#pragma unroll
  for (int r = 0; r < 8; ++r) {
    if (bb[r] >= 0)
      stage[sc[bb[r]] + pp[r]] = ((unsigned)bb[r] << 22) | (unsigned)ent[r];
  }
  __syncthreads();
  for (int i = tid; i < total; i += 1024) {
    unsigned pe = stage[i];
    int b = pe >> 22;
    int addr = gofs[b] + i;
    if (addr < b * CAP_C + CAP_C)  // statistical overflow guard (22 sigma)
      buf[addr] = (int)(pe & 0x3FFFFFu);
  }
}

// Fused layer-1 gather: one 512-thread block per 64-node bucket. In-block
// dst-sort, then per-node segments accumulated in registers (no fp atomics).
__global__ __launch_bounds__(512) void gather1(
    const int* __restrict__ bcnt, const int* __restrict__ buf,
    const __half* __restrict__ xlh, const float* __restrict__ xr,
    const float* __restrict__ att, const float* __restrict__ b1,
    const float* __restrict__ W2l, const float* __restrict__ W2r,
    float* __restrict__ hl, float* __restrict__ hr, int N) {
  __shared__ int hist[64];      // per-node edge counts
  __shared__ int ofs[64];       // per-node segment start
  __shared__ int ents2[CAP_C];  // src ids, dst-sorted
  int bucket = blockIdx.x;
  int tid = threadIdx.x;
  int w = tid >> 6, lane = tid & 63;
  int cnt = min(bcnt[bucket * CNT_STRIDE], CAP_C);
  if (tid < 64) hist[tid] = 0;
  __syncthreads();
  // phase 1: read entries (coalesced), rank within dst node (static slots)
  const int* __restrict__ bseg = buf + (size_t)bucket * CAP_C;
  int dv[6], rv[6], sv[6];
  bool hv[6];
#pragma unroll
  for (int r = 0; r < 6; ++r) {
    int i = tid + r * 512;
    hv[r] = i < cnt;
    dv[r] = 0; rv[r] = 0; sv[r] = 0;
    if (hv[r]) {
      int e = bseg[i];
      dv[r] = e & CB_MASK; sv[r] = e >> CB_SHIFT;
      rv[r] = atomicAdd(&hist[dv[r]], 1);
    }
  }
  __syncthreads();
  // phase 2: exclusive scan of hist (first wave, shfl)
  if (tid < 64) {
    int v = hist[tid];
    int inc = v;
#pragma unroll
    for (int off = 1; off < 64; off <<= 1) {
      int u = __shfl_up(inc, off);
      if (lane >= off) inc += u;
    }
    ofs[tid] = inc - v;
  }
  __syncthreads();
  // phase 3: place srcs into dst-sorted ents2
#pragma unroll
  for (int r = 0; r < 6; ++r)
    if (hv[r]) ents2[ofs[dv[r]] + rv[r]] = sv[r];
  __syncthreads();
  // phase 4: wave w accumulates nodes 8w..8w+7 in registers, 4-deep pipeline
  int nbase = bucket << CB_SHIFT;
  float av = att[lane] * LOG2E;  // exp(p) == exp2(p*log2e)
  float b1v = b1[lane], w2lv = W2l[lane], w2rv = W2r[lane];
#pragma unroll
  for (int r8 = 0; r8 < 8; ++r8) {
    int r = (w << 3) | r8;
    int nn = nbase + r;
    if (nn >= N) continue;  // wave-uniform branch
    float bv = xr[((size_t)nn << 6) + lane];
    float acc, den;
    {  // self loop
      float a = __half2float(xlh[((size_t)nn << 6) + lane]);
      float t = a + bv; t = fmaxf(t, NEG_SLOPE * t);
      float wgt = EXP2(head8_sum(t * av));
      acc = wgt * a; den = wgt;
    }
    int beg = ofs[r], end = beg + hist[r];
    int j = beg;
    for (; j + 3 < end; j += 4) {  // 4-deep gather pipeline
      int s0 = __builtin_amdgcn_readfirstlane(ents2[j]);
      int s1 = __builtin_amdgcn_readfirstlane(ents2[j + 1]);
      int s2 = __builtin_amdgcn_readfirstlane(ents2[j + 2]);
      int s3 = __builtin_amdgcn_readfirstlane(ents2[j + 3]);
      float a0 = __half2float(xlh[((size_t)s0 << 6) + lane]);
      float a1 = __half2float(xlh[((size_t)s1 << 6) + lane]);
      float a2 = __half2float(xlh[((size_t)s2 << 6) + lane]);
      float a3 = __half2float(xlh[((size_t)s3 << 6) + lane]);
      float t0 = a0 + bv; t0 = fmaxf(t0, NEG_SLOPE * t0);
      float t1 = a1 + bv; t1 = fmaxf(t1, NEG_SLOPE * t1);
      float t2 = a2 + bv; t2 = fmaxf(t2, NEG_SLOPE * t2);
      float t3 = a3 + bv; t3 = fmaxf(t3, NEG_SLOPE * t3);
      float w0 = EXP2(head8_sum(t0 * av));
      float w1 = EXP2(head8_sum(t1 * av));
      float w2 = EXP2(head8_sum(t2 * av));
      float w3 = EXP2(head8_sum(t3 * av));
      acc = fmaf(w0, a0, acc); den += w0;
      acc = fmaf(w1, a1, acc); den += w1;
      acc = fmaf(w2, a2, acc); den += w2;
      acc = fmaf(w3, a3, acc); den += w3;
    }
    for (; j < end; ++j) {
      int s0 = __builtin_amdgcn_readfirstlane(ents2[j]);
      float a0 = __half2float(xlh[((size_t)s0 << 6) + lane]);
      float t0 = a0 + bv; t0 = fmaxf(t0, NEG_SLOPE * t0);
      float w0 = EXP2(head8_sum(t0 * av));
      acc = fmaf(w0, a0, acc); den += w0;
    }
    // normalize, +b1, ELU, project to layer-2 scalars
    float v = acc / den + b1v;
    float h = v > 0.f ? v : (__expf(v) - 1.f);  // ELU(alpha=1)
    float pl = h * w2lv;
    float pr = h * w2rv;
#pragma unroll
    for (int off = 1; off < 64; off <<= 1) {
      pl += __shfl_xor(pl, off);
      pr += __shfl_xor(pr, off);
    }
    if (lane == 0) { hl[nn] = pl; hr[nn] = pr; }
  }
}

// Layer-2 gather: one 512-thread block per bucket, edge-parallel; LDS num/den
// per node (few atomic wave-ops total; hl/hr are L2-resident).
__global__ __launch_bounds__(512) void gather2(
    const int* __restrict__ bcnt, const int* __restrict__ buf,
    const float* __restrict__ hl, const float* __restrict__ hr,
    const float* __restrict__ att2, const float* __restrict__ b2,
    float* __restrict__ out, int N) {
  __shared__ float hrs[64];
  __shared__ float num[64];
  __shared__ float den[64];
  int bucket = blockIdx.x;
  int tid = threadIdx.x;
  int cnt = min(bcnt[bucket * CNT_STRIDE], CAP_C);
  int nbase = bucket << CB_SHIFT;
  float a2 = att2[0] * LOG2E;
  if (tid < 64) {  // stage hr + self-loop init
    int nn = nbase + tid;
    if (nn < N) {
      float hld = hl[nn], hrd = hr[nn];
      hrs[tid] = hrd;
      float t = hld + hrd;
      t = fmaxf(t, NEG_SLOPE * t);
      float wgt = EXP2(t * a2);
      num[tid] = wgt * hld;
      den[tid] = wgt;
    } else {
      hrs[tid] = 0.f; num[tid] = 0.f; den[tid] = 1.f;
    }
  }
  __syncthreads();
  const int* __restrict__ bseg = buf + (size_t)bucket * CAP_C;
  for (int i = tid; i < cnt; i += 512) {
    int e = bseg[i];
    int s = e >> CB_SHIFT, dl = e & CB_MASK;
    float hls = hl[s];
    float t = hls + hrs[dl];
    t = fmaxf(t, NEG_SLOPE * t);
    float wgt = EXP2(t * a2);
    lds_fadd(&num[dl], wgt * hls);
    lds_fadd(&den[dl], wgt);
  }
  __syncthreads();
  if (tid < 64) {
    int nn = nbase + tid;
    if (nn < N) out[nn] = num[tid] / den[tid] + b2[0];
  }
}

extern "C" void kernel_launch(void* const* d_in, const int* in_sizes, int n_in,
                              void* d_out, int out_size, void* d_ws, size_t ws_size,
                              hipStream_t stream) {
  const float* x    = (const float*)d_in[0];
  const int*   ei   = (const int*)d_in[1];
  const float* W1l  = (const float*)d_in[2];
  const float* W1r  = (const float*)d_in[3];
  const float* att1 = (const float*)d_in[4];
  const float* b1   = (const float*)d_in[5];
  const float* W2l  = (const float*)d_in[6];
  const float* W2r  = (const float*)d_in[7];
  const float* att2 = (const float*)d_in[8];
  const float* b2   = (const float*)d_in[9];
  float* out = (float*)d_out;

  const int N  = in_sizes[0] / 128;          // 50000
  const int E0 = in_sizes[1] / 2;            // 1600000
  const int NB = (N + CB_MASK) >> CB_SHIFT;  // 782 buckets of 64 nodes

  // workspace layout
  float* ws  = (float*)d_ws;
  size_t NF  = (size_t)N * 64;
  __half* xlh = (__half*)ws;          // N*64 halves (= N*32 floats)
  float* xr  = ws + (size_t)N * 32;   // N*64
  float* hl  = xr + NF;               // N
  float* hr  = hl + N;                // N
  int* bcnt  = (int*)(hr + N);                  // NB*CNT_STRIDE (zeroed)
  int* buf   = bcnt + (size_t)NB * CNT_STRIDE;  // NB*CAP_C

  hipMemsetAsync(bcnt, 0, (size_t)NB * CNT_STRIDE * sizeof(int), stream);

  const int GEMM_HALF = 512;  // blocks per W-panel (2048 waves each)
  gemm_reg_dual<<<GEMM_HALF * 2, 256, 0, stream>>>(x, W1l, W1r, xlh, xr, N,
                                                   GEMM_HALF);
  bucket_scatter<<<(E0 + CHUNK - 1) / CHUNK, 1024, 0, stream>>>(ei, E0, bcnt, buf);
  gather1<<<NB, 512, 0, stream>>>(bcnt, buf, xlh, xr, att1, b1, W2l, W2r,
                                  hl, hr, N);
  gather2<<<NB, 512, 0, stream>>>(bcnt, buf, hl, hr, att2, b2, out, N);
}